// Round 13
// baseline (404.784 us; speedup 1.0000x reference)
//
#include <hip/hip_runtime.h>

typedef __bf16 bf16_t;
typedef bf16_t bf16x8 __attribute__((ext_vector_type(8)));
typedef float f32x4 __attribute__((ext_vector_type(4)));
typedef unsigned short ushortx8 __attribute__((ext_vector_type(8)));
typedef unsigned short ushortx4 __attribute__((ext_vector_type(4)));
typedef short short4v __attribute__((ext_vector_type(4)));

union UB8 { bf16_t h8[8]; bf16x8 b; };

// native RNE float->bf16 (gfx950 v_cvt_*_bf16_f32)
__device__ __forceinline__ unsigned short f2bf(float f) {
  union { bf16_t h; unsigned short u; } cv;
  cv.h = (bf16_t)f;
  return cv.u;
}

// async global->LDS, 16B per lane; LDS dest is wave-uniform base + lane*16
__device__ __forceinline__ void gl_lds16(const unsigned short* g, unsigned short* l) {
  __builtin_amdgcn_global_load_lds((const __attribute__((address_space(1))) void*)g,
                                   (__attribute__((address_space(3))) void*)l,
                                   16, 0, 0);
}

// fast GELU: tanh form as sigmoid; max abs err ~3e-4 vs exact erf
__device__ __forceinline__ float gelu_fast(float v) {
  float v3 = v * v * v;
  float z = -2.30211886f * v - 0.102945f * v3;
  float e = exp2f(z);
  return v * __builtin_amdgcn_rcpf(1.0f + e);
}

// ---------------------------------------------------------------------------
// LayerNorm: fp32 [rows x 768] -> bf16 bits [rows x 768]
// ---------------------------------------------------------------------------
__global__ __launch_bounds__(256) void ln_kernel(const float* __restrict__ x,
                                                 const float* __restrict__ g,
                                                 const float* __restrict__ b,
                                                 unsigned short* __restrict__ out) {
  int row = blockIdx.x;
  int t = threadIdx.x;
  const float* xr = x + (size_t)row * 768;
  float v0 = xr[t], v1 = xr[t + 256], v2 = xr[t + 512];
  __shared__ float red[4];
  float s = v0 + v1 + v2;
  for (int o = 32; o > 0; o >>= 1) s += __shfl_down(s, o, 64);
  if ((t & 63) == 0) red[t >> 6] = s;
  __syncthreads();
  float mu = (red[0] + red[1] + red[2] + red[3]) * (1.0f / 768.0f);
  __syncthreads();
  float d0 = v0 - mu, d1 = v1 - mu, d2 = v2 - mu;
  s = d0 * d0 + d1 * d1 + d2 * d2;
  for (int o = 32; o > 0; o >>= 1) s += __shfl_down(s, o, 64);
  if ((t & 63) == 0) red[t >> 6] = s;
  __syncthreads();
  float var = (red[0] + red[1] + red[2] + red[3]) * (1.0f / 768.0f);
  float rs = rsqrtf(var + 1e-6f);
  unsigned short* orow = out + (size_t)row * 768;
  orow[t]       = f2bf(d0 * rs * g[t]       + b[t]);
  orow[t + 256] = f2bf(d1 * rs * g[t + 256] + b[t + 256]);
  orow[t + 512] = f2bf(d2 * rs * g[t + 512] + b[t + 512]);
}

// ---------------------------------------------------------------------------
// All 4 weight transposes in ONE launch. fp32 [K x N] -> bf16 [N x K].
// ---------------------------------------------------------------------------
__global__ __launch_bounds__(256) void transpose_all(
    const float* __restrict__ w_qkv, const float* __restrict__ w_attn,
    const float* __restrict__ w_in, const float* __restrict__ w_out,
    unsigned short* __restrict__ wqkvT, unsigned short* __restrict__ wattnT,
    unsigned short* __restrict__ winT, unsigned short* __restrict__ woutT) {
  int id = blockIdx.x;
  const float* W; unsigned short* WT; int K, N, nx, ny;
  if (id < 1728)      { W = w_qkv;  WT = wqkvT;  K = 768;  N = 2304; nx = id % 72; ny = id / 72; }
  else if (id < 2304) { id -= 1728; W = w_attn; WT = wattnT; K = 768;  N = 768;  nx = id % 24; ny = id / 24; }
  else if (id < 4608) { id -= 2304; W = w_in;   WT = winT;   K = 768;  N = 3072; nx = id % 96; ny = id / 96; }
  else                { id -= 4608; W = w_out;  WT = woutT;  K = 3072; N = 768;  nx = id % 24; ny = id / 24; }
  __shared__ float tile[32][33];
  int n0 = nx * 32, k0 = ny * 32;
  int tx = threadIdx.x, ty = threadIdx.y;
  for (int i = 0; i < 4; i++)
    tile[ty + i * 8][tx] = W[(size_t)(k0 + ty + i * 8) * N + n0 + tx];
  __syncthreads();
  for (int i = 0; i < 4; i++)
    WT[(size_t)(n0 + ty + i * 8) * K + k0 + tx] = f2bf(tile[tx][ty + i * 8]);
}

// ---------------------------------------------------------------------------
// GEMM body v20. Two paths:
// - DEEP=false: v17 (4 bufs, 1 barrier/2kt, vmcnt(0) drain) -- qkv TM=128.
// - DEEP=true  (TM=64 kernels): 6 bufs, SAME barrier cadence (1 per 2 kt),
//   but counted wait vmcnt(6): at every barrier the NEWEST stage batch
//   {kt+2,kt+3} stays in flight and {kt,kt+1} were issued TWO periods ago --
//   the load stream never drains (m233: the stage+vmcnt+bar stall was 72% of
//   a 2-phase loop; R11 showed counted-vmcnt helps only if barrier count
//   doesn't grow -- here it stays at nk/2). Cost: 72KB LDS -> 2 blocks/CU
//   (was 3). Induction: prologue stages {0..3}; wait(6) drains oldest batch;
//   stage (kt+4)%6 overwrites {kt-2,kt-1}, consumed before this barrier
//   (ds_reads retire before MFMA use); tail vmcnt(6) while kt+2<nk, else 0.
// ---------------------------------------------------------------------------
template <int EPI, int TM, bool DEEP>
__device__ __forceinline__ void gemm_body(const unsigned short* __restrict__ A,
                                          const unsigned short* __restrict__ BT,
                                          const float* __restrict__ bias,
                                          const float* resid,
                                          void* out, unsigned short* vt, int os,
                                          int N, int K) {
  constexpr int BK = 32, MI = TM / 32;
  constexpr int ASZ = TM * BK;        // shorts per A sub-buffer
  constexpr int BUF = ASZ + 128 * BK; // shorts per pipeline buffer
  constexpr int NBUF = DEEP ? 6 : 4;
  __shared__ __align__(16) unsigned short smem[NBUF * BUF];

  int t = threadIdx.x;
  int w = t >> 6, lane = t & 63, ln = lane & 15, quad = lane >> 4;
  int wm = w & 1, wn = w >> 1;

  // T1: bijective XCD chunk remap (all grids are multiples of 8)
  int gx = gridDim.x;
  int nwg = gx * gridDim.y;
  int flat = blockIdx.y * gx + blockIdx.x;
  int nf = (flat & 7) * (nwg >> 3) + (flat >> 3);
  int m0 = (nf / gx) * TM, n0 = (nf % gx) * 128;

  int lrow = lane >> 2;   // 0..15: row within 16-row load chunk
  int lslot = lane & 3;   // 16B slot within row
  int scol = (lslot ^ ((lrow >> 1) & 3)) * 8;  // pre-swizzled global column

  const unsigned short* gA0 = A + (size_t)(m0 + w * 16 + lrow) * K + scol;
  const unsigned short* gA1 = gA0 + (size_t)64 * K;
  const unsigned short* gB0 = BT + (size_t)(n0 + w * 16 + lrow) * K + scol;
  const unsigned short* gB1 = gB0 + (size_t)64 * K;

  auto stage = [&](int buf) {
    unsigned short* Sb = smem + buf * BUF;
    gl_lds16(gA0, Sb + w * 512);
    gA0 += BK;
    if constexpr (TM == 128) { gl_lds16(gA1, Sb + 2048 + w * 512); gA1 += BK; }
    gl_lds16(gB0, Sb + ASZ + w * 512);
    gl_lds16(gB1, Sb + ASZ + 2048 + w * 512);
    gB0 += BK; gB1 += BK;
  };

  f32x4 acc[MI][4];
  f32x4 zero = {0.f, 0.f, 0.f, 0.f};
  for (int mi = 0; mi < MI; mi++)
    for (int ni = 0; ni < 4; ni++) acc[mi][ni] = zero;

  int soff = (quad ^ ((ln >> 1) & 3)) * 8;  // fragment slot (inverse swizzle)

  auto compute = [&](int buf) {
    const unsigned short* Sc = smem + buf * BUF;
    bf16x8 af[MI], bfr[4];
#pragma unroll
    for (int mi = 0; mi < MI; mi++)
      af[mi] = *(const bf16x8*)&Sc[(wm * (TM / 2) + mi * 16 + ln) * 32 + soff];
#pragma unroll
    for (int ni = 0; ni < 4; ni++)
      bfr[ni] = *(const bf16x8*)&Sc[ASZ + (wn * 64 + ni * 16 + ln) * 32 + soff];
    __builtin_amdgcn_s_setprio(1);
#pragma unroll
    for (int mi = 0; mi < MI; mi++)
#pragma unroll
      for (int ni = 0; ni < 4; ni++)
        acc[mi][ni] = __builtin_amdgcn_mfma_f32_16x16x32_bf16(af[mi], bfr[ni],
                                                              acc[mi][ni], 0, 0, 0);
    __builtin_amdgcn_s_setprio(0);
  };

  int nk = K / BK;  // 24 or 96
  if constexpr (DEEP) {
    stage(0); stage(1); stage(2); stage(3);  // kts 0..3 (two batches)
    for (int kt = 0; kt < nk; kt += 2) {
      // drain ONLY the {kt,kt+1} batch (issued 2 periods ago); the
      // {kt+2,kt+3} batch (1 period ago) stays in flight across the barrier
      if (kt + 2 < nk) {
        if constexpr (TM == 128) asm volatile("s_waitcnt vmcnt(8)" ::: "memory");
        else                     asm volatile("s_waitcnt vmcnt(6)" ::: "memory");
      } else {
        asm volatile("s_waitcnt vmcnt(0)" ::: "memory");
      }
      __builtin_amdgcn_s_barrier();
      __builtin_amdgcn_sched_barrier(0);
      if (kt + 4 < nk) {  // overwrite bufs of {kt-2,kt-1}: consumed pre-barrier
        stage((kt + 4) % 6);
        stage((kt + 5) % 6);
      }
      compute(kt % 6);
      compute((kt + 1) % 6);
    }
  } else {
    stage(0); stage(1);  // ONE iteration's worth only
    for (int kt = 0; kt < nk; kt += 2) {
      asm volatile("s_waitcnt vmcnt(0)" ::: "memory");
      __builtin_amdgcn_s_barrier();
      __builtin_amdgcn_sched_barrier(0);
      if (kt + 2 < nk) {
        stage((kt + 2) & 3);
        stage((kt + 3) & 3);
      }
      compute(kt & 3);
      compute((kt + 1) & 3);
    }
  }

  if (EPI == 2) {
    float* outp = (float*)out;
    for (int mi = 0; mi < MI; mi++) {
      for (int ni = 0; ni < 4; ni++) {
        int col = n0 + wn * 64 + ni * 16 + ln;
        float bv = bias[col];
        for (int r = 0; r < 4; r++) {
          int row = m0 + wm * (TM / 2) + mi * 16 + quad * 4 + r;
          float v = acc[mi][ni][r] + bv;
          v += resid[(size_t)row * N + col];
          outp[(size_t)row * N + col] = v;
        }
      }
    }
  } else {
    __syncthreads();  // all waves done with K-loop smem before Cs16 reuse
    unsigned short* Cs16 = smem + w * 1024;
    unsigned short* outp = (unsigned short*)out;
    for (int mi = 0; mi < MI; mi++) {
      for (int ni = 0; ni < 4; ni++) {
        int col = n0 + wn * 64 + ni * 16 + ln;
        float bv = bias[col];
        for (int r = 0; r < 4; r++) {
          float v = acc[mi][ni][r] + bv;
          if (EPI == 0) {
            if (col < 768) v *= 0.18033688f;  // hd^-0.5 * log2(e)
          } else {
            v = gelu_fast(v);
          }
          Cs16[(quad * 4 + r) * 64 + ni * 16 + ln] = f2bf(v);
        }
      }
      __syncthreads();  // fence: scalar ds_writes visible before reads
      if (EPI == 0 && n0 >= 1536) {
        int c = n0 - 1536 + wn * 64 + lane;  // h*64+d
        int s0 = m0 + wm * (TM / 2) + mi * 16;
        int bb = s0 >> 11, sl = s0 & 2047;
        ushortx8 lo, hi;
        for (int r = 0; r < 8; r++) lo[r] = Cs16[r * 64 + lane];
        for (int r = 0; r < 8; r++) hi[r] = Cs16[(8 + r) * 64 + lane];
        size_t vbase = ((size_t)(bb * 768 + c)) * 2048 + sl;
        *(ushortx8*)&vt[vbase] = lo;
        *(ushortx8*)&vt[vbase + 8] = hi;
      } else {
        int OS = (EPI == 0) ? os : N;
        for (int j = 0; j < 2; j++) {
          int rrow = j * 8 + (lane >> 3);
          int ch = (lane & 7) * 8;
          ushortx8 pv = *(const ushortx8*)&Cs16[rrow * 64 + ch];
          *(ushortx8*)&outp[(size_t)(m0 + wm * (TM / 2) + mi * 16 + rrow) * OS +
                            n0 + wn * 64 + ch] = pv;
        }
      }
      __syncthreads();
    }
  }
}

__global__ __launch_bounds__(256) void gemm_qkv(const unsigned short* A,
    const unsigned short* BT, const float* bias, void* out, unsigned short* vt,
    int N, int K) {
  gemm_body<0, 128, false>(A, BT, bias, nullptr, out, vt, 1536, N, K);
}
__global__ __launch_bounds__(256) void gemm_attnout(const unsigned short* A,
    const unsigned short* BT, const float* bias, const float* resid, void* out,
    int N, int K) {
  gemm_body<2, 64, true>(A, BT, bias, resid, out, nullptr, N, N, K);
}
__global__ __launch_bounds__(256) void gemm_ffn1(const unsigned short* A,
    const unsigned short* BT, const float* bias, void* out, int N, int K) {
  gemm_body<1, 64, true>(A, BT, bias, nullptr, out, nullptr, N, N, K);
}
__global__ __launch_bounds__(256) void gemm_ffn2(const unsigned short* A,
    const unsigned short* BT, const float* bias, const float* resid, void* out,
    int N, int K) {
  gemm_body<2, 64, true>(A, BT, bias, resid, out, nullptr, N, N, K);
}

// ---------------------------------------------------------------------------
// Flash attention v9: K rows stored PERMUTED in LDS so both kf exp-halves
// pack into ONE bf16x8 B-operand -> PV and l-sum use full-rate x32 MFMAs.
// ---------------------------------------------------------------------------
__global__ __launch_bounds__(512, 4) void flash_attn(
    const unsigned short* __restrict__ qk, const unsigned short* __restrict__ v_t,
    unsigned short* __restrict__ o) {
  int flat = blockIdx.y * 16 + blockIdx.x;
  int nf = (flat & 7) * 96 + (flat >> 3);  // 768 blocks, bijective
  int qt = nf % 16;  // 0..15
  int bh = nf / 16;  // 0..47
  int b = bh / 12, h = bh % 12;
  int t = threadIdx.x;
  int w = t >> 6, lane = t & 63, ln = lane & 15, quad = lane >> 4;
  int qg = w & 3, kh2 = w >> 2;  // 32-q group, 32-key half

  __shared__ __align__(16) unsigned short smem[18432];  // 36,864 B
  int qrow0 = b * 2048 + qt * 128;
  int qw = qrow0 + qg * 32;

  // Q as B-operand frags (k=d, n=q), loaded once
  bf16x8 qf[2][2];
  for (int qi = 0; qi < 2; qi++)
    for (int kh = 0; kh < 2; kh++)
      qf[qi][kh] = *(const bf16x8*)&qk[(size_t)(qw + qi * 16 + ln) * 1536 +
                                      h * 64 + kh * 32 + quad * 8];

  UB8 ones8;
#pragma unroll
  for (int r = 0; r < 8; r++) ones8.h8[r] = (bf16_t)1.0f;

  f32x4 zero = {0.f, 0.f, 0.f, 0.f};
  f32x4 o_acc[4][2];  // [df][qi]: O^T partial (this key-half), row=d, col=q
  for (int df = 0; df < 4; df++)
    for (int qi = 0; qi < 2; qi++) o_acc[df][qi] = zero;
  f32x4 l_acc[2] = {zero, zero};  // all 4 regs equal the column sum

  int sr = t >> 3, sc = (t & 7) * 8;  // 512 threads: 64x64 tile in one pass
  // K-row permutation: key bits [b5][b4 b3][b2][b1 b0] -> slot [b5][b2][b4 b3][b1 b0]
  int ssr = (sr & 32) | (((sr >> 2) & 1) << 4) | (((sr >> 3) & 3) << 2) | (sr & 3);
  // prefetch kt=0
  ushortx8 kreg = *(const ushortx8*)&qk[(size_t)(b * 2048 + sr) * 1536 + 768 + h * 64 + sc];
  ushortx8 vreg = *(const ushortx8*)&v_t[(size_t)(bh * 64 + sr) * 2048 + sc];

  for (int kt = 0; kt < 32; kt++) {
    unsigned short* Ks = smem + (kt & 1) * 9216;
    unsigned short* Vt = Ks + 4608;
    // safe: all waves passed barrier kt-1 which drained their kt-2 reads of
    // this parity's buffer
    *(ushortx8*)&Ks[ssr * 72 + sc] = kreg;  // permuted K row placement
    *(ushortx8*)&Vt[sr * 72 + sc] = vreg;
    __syncthreads();
    if (kt < 31) {  // prefetch next tile; overlaps compute below
      int krow0 = b * 2048 + (kt + 1) * 64;
      kreg = *(const ushortx8*)&qk[(size_t)(krow0 + sr) * 1536 + 768 + h * 64 + sc];
      vreg = *(const ushortx8*)&v_t[(size_t)(bh * 64 + sr) * 2048 + (kt + 1) * 64 + sc];
    }

    UB8 pb[2];
#pragma unroll
    for (int kf = 0; kf < 2; kf++) {  // two 16-slot sub-tiles of our key half
      int krow = kh2 * 32 + kf * 16;  // LDS slot base (permuted key order)
      f32x4 ST[2] = {zero, zero};
      bf16x8 kA0 = *(const bf16x8*)&Ks[(krow + ln) * 72 + quad * 8];
      bf16x8 kA1 = *(const bf16x8*)&Ks[(krow + ln) * 72 + 32 + quad * 8];
      __builtin_amdgcn_s_setprio(1);
#pragma unroll
      for (int qi = 0; qi < 2; qi++) {
        ST[qi] = __builtin_amdgcn_mfma_f32_16x16x32_bf16(kA0, qf[qi][0], ST[qi], 0, 0, 0);
        ST[qi] = __builtin_amdgcn_mfma_f32_16x16x32_bf16(kA1, qf[qi][1], ST[qi], 0, 0, 0);
      }
      __builtin_amdgcn_s_setprio(0);
      // lane(quad,r) of kf holds key quad*8 + kf*4 + r (by the sigma perm)
#pragma unroll
      for (int qi = 0; qi < 2; qi++)
#pragma unroll
        for (int r = 0; r < 4; r++)
          pb[qi].h8[kf * 4 + r] = (bf16_t)__builtin_amdgcn_exp2f(ST[qi][r]);
    }
    // pb[qi] is the full 16x16x32 B-operand: col=q(ln), k=key quad*8+j
    __builtin_amdgcn_s_setprio(1);
#pragma unroll
    for (int qi = 0; qi < 2; qi++)
      l_acc[qi] = __builtin_amdgcn_mfma_f32_16x16x32_bf16(ones8.b, pb[qi].b,
                                                          l_acc[qi], 0, 0, 0);
#pragma unroll
    for (int df = 0; df < 4; df++) {
      bf16x8 vA = *(const bf16x8*)&Vt[(df * 16 + ln) * 72 + kh2 * 32 + quad * 8];
#pragma unroll
      for (int qi = 0; qi < 2; qi++)
        o_acc[df][qi] = __builtin_amdgcn_mfma_f32_16x16x32_bf16(vA, pb[qi].b,
                                                                o_acc[df][qi], 0, 0, 0);
    }
    __builtin_amdgcn_s_setprio(0);
  }

  // ---- split-K merge + output ----
  // fb stride 65: bank = (65*q + d) % 32 = (q + d) % 32 -> q-lanes spread
  __syncthreads();  // all compute done; smem reusable
  float* fb = (float*)smem;           // [4 pairs][32q x 65] fp32
  float* fbl = fb + 8320;             // [4 pairs][32q] l partials
  if (kh2 == 1) {
    for (int df = 0; df < 4; df++)
      for (int qi = 0; qi < 2; qi++)
        for (int r = 0; r < 4; r++)
          fb[qg * 2080 + (qi * 16 + ln) * 65 + df * 16 + quad * 4 + r] =
              o_acc[df][qi][r];
    if (quad == 0)
      for (int qi = 0; qi < 2; qi++)
        fbl[qg * 32 + qi * 16 + ln] = l_acc[qi][0];
  }
  __syncthreads();
  float inv[2];
  if (kh2 == 0) {
    for (int qi = 0; qi < 2; qi++) {
      float lt = l_acc[qi][0] + fbl[qg * 32 + qi * 16 + ln];
      inv[qi] = __builtin_amdgcn_rcpf(lt);
    }
    for (int df = 0; df < 4; df++)
      for (int qi = 0; qi < 2; qi++)
        for (int r = 0; r < 4; r++)
          o_acc[df][qi][r] += fb[qg * 2080 + (qi * 16 + ln) * 65 + df * 16 + quad * 4 + r];
  }
  __syncthreads();  // fb reads done before Osm overwrite
  if (kh2 == 0) {
    unsigned short* Osm = smem + qg * 2304;  // 32 x 72
    for (int qi = 0; qi < 2; qi++)
      for (int df = 0; df < 4; df++)
        for (int r = 0; r < 4; r++)
          Osm[(qi * 16 + ln) * 72 + df * 16 + quad * 4 + r] =
              f2bf(o_acc[df][qi][r] * inv[qi]);
  }
  __syncthreads();  // fence scalar ds_writes vs vector ds_reads
  if (kh2 == 0) {
    unsigned short* Osm = smem + qg * 2304;
    for (int p2 = 0; p2 < 4; p2++) {
      int rr = p2 * 8 + (lane >> 3);
      int ch = (lane & 7) * 8;
      ushortx8 u = *(const ushortx8*)&Osm[rr * 72 + ch];
      *(ushortx8*)&o[(size_t)(qw + rr) * 768 + h * 64 + ch] = u;
    }
  }
}

// ---------------------------------------------------------------------------
extern "C" void kernel_launch(void* const* d_in, const int* in_sizes, int n_in,
                              void* d_out, int out_size, void* d_ws, size_t ws_size,
                              hipStream_t stream) {
  const float* hidden = (const float*)d_in[0];
  const float* ln1_g  = (const float*)d_in[1];
  const float* ln1_b  = (const float*)d_in[2];
  const float* w_qkv  = (const float*)d_in[3];
  const float* b_qkv  = (const float*)d_in[4];
  const float* w_attn = (const float*)d_in[5];
  const float* b_attn = (const float*)d_in[6];
  const float* ln2_g  = (const float*)d_in[7];
  const float* ln2_b  = (const float*)d_in[8];
  const float* w_in   = (const float*)d_in[9];
  const float* b_in   = (const float*)d_in[10];
  const float* w_out  = (const float*)d_in[11];
  const float* b_out  = (const float*)d_in[12];
  float* out = (float*)d_out;

  char* ws = (char*)d_ws;
  unsigned short* wqkvT  = (unsigned short*)(ws + 0);         // 2304x768 bf16
  unsigned short* wattnT = (unsigned short*)(ws + 3538944);   //  768x768
  unsigned short* winT   = (unsigned short*)(ws + 4718592);   // 3072x768
  unsigned short* woutT  = (unsigned short*)(ws + 9437184);   //  768x3072
  unsigned short* bufX   = (unsigned short*)(ws + 14155776);  // 8192x768 bf16
  unsigned short* bufBig = (unsigned short*)(ws + 26738688);  // 8192x3072 bf16
  unsigned short* bufQK  = bufBig;                            // 8192x1536 bf16
  unsigned short* v_t    = (unsigned short*)(ws + 26738688 + 25165824);  // V^T

  transpose_all<<<6912, dim3(32, 8), 0, stream>>>(w_qkv, w_attn, w_in, w_out,
                                                  wqkvT, wattnT, winT, woutT);
  ln_kernel<<<8192, 256, 0, stream>>>(hidden, ln1_g, ln1_b, bufX);
  gemm_qkv<<<dim3(18, 64), 256, 0, stream>>>(bufX, wqkvT, b_qkv, (void*)bufQK,
                                             v_t, 2304, 768);
  flash_attn<<<dim3(16, 48), 512, 0, stream>>>(bufQK, v_t, bufX);
  gemm_attnout<<<dim3(6, 128), 256, 0, stream>>>(bufX, wattnT, b_attn, hidden,
                                                 (void*)out, 768, 768);
  ln_kernel<<<8192, 256, 0, stream>>>(out, ln2_g, ln2_b, bufX);
  gemm_ffn1<<<dim3(24, 128), 256, 0, stream>>>(bufX, winT, b_in, (void*)bufBig,
                                               3072, 768);
  gemm_ffn2<<<dim3(6, 128), 256, 0, stream>>>(bufBig, woutT, b_out, out,
                                              (void*)out, 768, 3072);
}

// Round 15
// 373.575 us; speedup vs baseline: 1.0835x; 1.0835x over previous
//
#include <hip/hip_runtime.h>

typedef __bf16 bf16_t;
typedef bf16_t bf16x8 __attribute__((ext_vector_type(8)));
typedef float f32x4 __attribute__((ext_vector_type(4)));
typedef unsigned short ushortx8 __attribute__((ext_vector_type(8)));
typedef unsigned short ushortx4 __attribute__((ext_vector_type(4)));
typedef short short4v __attribute__((ext_vector_type(4)));

union UB8 { bf16_t h8[8]; bf16x8 b; };

// native RNE float->bf16 (gfx950 v_cvt_*_bf16_f32)
__device__ __forceinline__ unsigned short f2bf(float f) {
  union { bf16_t h; unsigned short u; } cv;
  cv.h = (bf16_t)f;
  return cv.u;
}

// async global->LDS, 16B per lane; LDS dest is wave-uniform base + lane*16
__device__ __forceinline__ void gl_lds16(const unsigned short* g, unsigned short* l) {
  __builtin_amdgcn_global_load_lds((const __attribute__((address_space(1))) void*)g,
                                   (__attribute__((address_space(3))) void*)l,
                                   16, 0, 0);
}

// fast GELU: tanh form as sigmoid; max abs err ~3e-4 vs exact erf
__device__ __forceinline__ float gelu_fast(float v) {
  float v3 = v * v * v;
  float z = -2.30211886f * v - 0.102945f * v3;
  float e = exp2f(z);
  return v * __builtin_amdgcn_rcpf(1.0f + e);
}

// ---------------------------------------------------------------------------
// LayerNorm: fp32 [rows x 768] -> bf16 bits [rows x 768]
// ---------------------------------------------------------------------------
__global__ __launch_bounds__(256) void ln_kernel(const float* __restrict__ x,
                                                 const float* __restrict__ g,
                                                 const float* __restrict__ b,
                                                 unsigned short* __restrict__ out) {
  int row = blockIdx.x;
  int t = threadIdx.x;
  const float* xr = x + (size_t)row * 768;
  float v0 = xr[t], v1 = xr[t + 256], v2 = xr[t + 512];
  __shared__ float red[4];
  float s = v0 + v1 + v2;
  for (int o = 32; o > 0; o >>= 1) s += __shfl_down(s, o, 64);
  if ((t & 63) == 0) red[t >> 6] = s;
  __syncthreads();
  float mu = (red[0] + red[1] + red[2] + red[3]) * (1.0f / 768.0f);
  __syncthreads();
  float d0 = v0 - mu, d1 = v1 - mu, d2 = v2 - mu;
  s = d0 * d0 + d1 * d1 + d2 * d2;
  for (int o = 32; o > 0; o >>= 1) s += __shfl_down(s, o, 64);
  if ((t & 63) == 0) red[t >> 6] = s;
  __syncthreads();
  float var = (red[0] + red[1] + red[2] + red[3]) * (1.0f / 768.0f);
  float rs = rsqrtf(var + 1e-6f);
  unsigned short* orow = out + (size_t)row * 768;
  orow[t]       = f2bf(d0 * rs * g[t]       + b[t]);
  orow[t + 256] = f2bf(d1 * rs * g[t + 256] + b[t + 256]);
  orow[t + 512] = f2bf(d2 * rs * g[t + 512] + b[t + 512]);
}

// ---------------------------------------------------------------------------
// All 4 weight transposes in ONE launch. fp32 [K x N] -> bf16 [N x K].
// ---------------------------------------------------------------------------
__global__ __launch_bounds__(256) void transpose_all(
    const float* __restrict__ w_qkv, const float* __restrict__ w_attn,
    const float* __restrict__ w_in, const float* __restrict__ w_out,
    unsigned short* __restrict__ wqkvT, unsigned short* __restrict__ wattnT,
    unsigned short* __restrict__ winT, unsigned short* __restrict__ woutT) {
  int id = blockIdx.x;
  const float* W; unsigned short* WT; int K, N, nx, ny;
  if (id < 1728)      { W = w_qkv;  WT = wqkvT;  K = 768;  N = 2304; nx = id % 72; ny = id / 72; }
  else if (id < 2304) { id -= 1728; W = w_attn; WT = wattnT; K = 768;  N = 768;  nx = id % 24; ny = id / 24; }
  else if (id < 4608) { id -= 2304; W = w_in;   WT = winT;   K = 768;  N = 3072; nx = id % 96; ny = id / 96; }
  else                { id -= 4608; W = w_out;  WT = woutT;  K = 3072; N = 768;  nx = id % 24; ny = id / 24; }
  __shared__ float tile[32][33];
  int n0 = nx * 32, k0 = ny * 32;
  int tx = threadIdx.x, ty = threadIdx.y;
  for (int i = 0; i < 4; i++)
    tile[ty + i * 8][tx] = W[(size_t)(k0 + ty + i * 8) * N + n0 + tx];
  __syncthreads();
  for (int i = 0; i < 4; i++)
    WT[(size_t)(n0 + ty + i * 8) * K + k0 + tx] = f2bf(tile[tx][ty + i * 8]);
}

// ---------------------------------------------------------------------------
// GEMM body v21 = v17 exactly (the best-measured structure: 4 bufs, 1 barrier
// per 2 kt, vmcnt(0) free-drain at the batched barrier, XOR swizzle, T1
// remap, setprio). 13 rounds of evidence: counted-vmcnt (R11 depth-3, R13
// 6-buf), B-in-registers (R5 depth-1, R9 depth-2), split-K atomics (R4),
// barrier-halving-beyond-2 -- all null-to-negative as grafts. Per-kernel tile
// choice from direct A/B: qkv TM=128 (TM=64 cost +18us B-refetch, R12);
// ffn1 TM=64 (74.2 vs 77.5, R12); ffn2/attnout TM=64 (R10/R12).
// (Round-14 bench was an infra container failure; identical resubmit.)
// ---------------------------------------------------------------------------
template <int EPI, int TM>
__device__ __forceinline__ void gemm_body(const unsigned short* __restrict__ A,
                                          const unsigned short* __restrict__ BT,
                                          const float* __restrict__ bias,
                                          const float* resid,
                                          void* out, unsigned short* vt, int os,
                                          int N, int K) {
  constexpr int BK = 32, MI = TM / 32;
  constexpr int ASZ = TM * BK;        // shorts per A sub-buffer
  constexpr int BUF = ASZ + 128 * BK; // shorts per pipeline buffer
  __shared__ __align__(16) unsigned short smem[4 * BUF];

  int t = threadIdx.x;
  int w = t >> 6, lane = t & 63, ln = lane & 15, quad = lane >> 4;
  int wm = w & 1, wn = w >> 1;

  // T1: bijective XCD chunk remap (all grids are multiples of 8)
  int gx = gridDim.x;
  int nwg = gx * gridDim.y;
  int flat = blockIdx.y * gx + blockIdx.x;
  int nf = (flat & 7) * (nwg >> 3) + (flat >> 3);
  int m0 = (nf / gx) * TM, n0 = (nf % gx) * 128;

  int lrow = lane >> 2;   // 0..15: row within 16-row load chunk
  int lslot = lane & 3;   // 16B slot within row
  int scol = (lslot ^ ((lrow >> 1) & 3)) * 8;  // pre-swizzled global column

  const unsigned short* gA0 = A + (size_t)(m0 + w * 16 + lrow) * K + scol;
  const unsigned short* gA1 = gA0 + (size_t)64 * K;
  const unsigned short* gB0 = BT + (size_t)(n0 + w * 16 + lrow) * K + scol;
  const unsigned short* gB1 = gB0 + (size_t)64 * K;

  auto stage = [&](int buf) {
    unsigned short* Sb = smem + buf * BUF;
    gl_lds16(gA0, Sb + w * 512);
    gA0 += BK;
    if constexpr (TM == 128) { gl_lds16(gA1, Sb + 2048 + w * 512); gA1 += BK; }
    gl_lds16(gB0, Sb + ASZ + w * 512);
    gl_lds16(gB1, Sb + ASZ + 2048 + w * 512);
    gB0 += BK; gB1 += BK;
  };

  f32x4 acc[MI][4];
  f32x4 zero = {0.f, 0.f, 0.f, 0.f};
  for (int mi = 0; mi < MI; mi++)
    for (int ni = 0; ni < 4; ni++) acc[mi][ni] = zero;

  int soff = (quad ^ ((ln >> 1) & 3)) * 8;  // fragment slot (inverse swizzle)

  auto compute = [&](int kt) {
    const unsigned short* Sc = smem + (kt & 3) * BUF;
    bf16x8 af[MI], bfr[4];
#pragma unroll
    for (int mi = 0; mi < MI; mi++)
      af[mi] = *(const bf16x8*)&Sc[(wm * (TM / 2) + mi * 16 + ln) * 32 + soff];
#pragma unroll
    for (int ni = 0; ni < 4; ni++)
      bfr[ni] = *(const bf16x8*)&Sc[ASZ + (wn * 64 + ni * 16 + ln) * 32 + soff];
    __builtin_amdgcn_s_setprio(1);
#pragma unroll
    for (int mi = 0; mi < MI; mi++)
#pragma unroll
      for (int ni = 0; ni < 4; ni++)
        acc[mi][ni] = __builtin_amdgcn_mfma_f32_16x16x32_bf16(af[mi], bfr[ni],
                                                              acc[mi][ni], 0, 0, 0);
    __builtin_amdgcn_s_setprio(0);
  };

  int nk = K / BK;  // 24 or 96: always >= 4 and even
  stage(0); stage(1);  // ONE iteration's worth only
  for (int kt = 0; kt < nk; kt += 2) {
    // only the {kt,kt+1} stage batches are outstanding: free drain
    asm volatile("s_waitcnt vmcnt(0)" ::: "memory");
    __builtin_amdgcn_s_barrier();
    __builtin_amdgcn_sched_barrier(0);
    if (kt + 2 < nk) {  // fill bufs of {kt-2,kt-1}: consumed pre-barrier
      stage((kt + 2) & 3);
      stage((kt + 3) & 3);
    }
    compute(kt);
    compute(kt + 1);
  }

  if (EPI == 2) {
    float* outp = (float*)out;
    for (int mi = 0; mi < MI; mi++) {
      for (int ni = 0; ni < 4; ni++) {
        int col = n0 + wn * 64 + ni * 16 + ln;
        float bv = bias[col];
        for (int r = 0; r < 4; r++) {
          int row = m0 + wm * (TM / 2) + mi * 16 + quad * 4 + r;
          float v = acc[mi][ni][r] + bv;
          v += resid[(size_t)row * N + col];
          outp[(size_t)row * N + col] = v;
        }
      }
    }
  } else {
    __syncthreads();  // all waves done with K-loop smem before Cs16 reuse
    unsigned short* Cs16 = smem + w * 1024;
    unsigned short* outp = (unsigned short*)out;
    for (int mi = 0; mi < MI; mi++) {
      for (int ni = 0; ni < 4; ni++) {
        int col = n0 + wn * 64 + ni * 16 + ln;
        float bv = bias[col];
        for (int r = 0; r < 4; r++) {
          float v = acc[mi][ni][r] + bv;
          if (EPI == 0) {
            if (col < 768) v *= 0.18033688f;  // hd^-0.5 * log2(e)
          } else {
            v = gelu_fast(v);
          }
          Cs16[(quad * 4 + r) * 64 + ni * 16 + ln] = f2bf(v);
        }
      }
      __syncthreads();  // fence: scalar ds_writes visible before reads
      if (EPI == 0 && n0 >= 1536) {
        int c = n0 - 1536 + wn * 64 + lane;  // h*64+d
        int s0 = m0 + wm * (TM / 2) + mi * 16;
        int bb = s0 >> 11, sl = s0 & 2047;
        ushortx8 lo, hi;
        for (int r = 0; r < 8; r++) lo[r] = Cs16[r * 64 + lane];
        for (int r = 0; r < 8; r++) hi[r] = Cs16[(8 + r) * 64 + lane];
        size_t vbase = ((size_t)(bb * 768 + c)) * 2048 + sl;
        *(ushortx8*)&vt[vbase] = lo;
        *(ushortx8*)&vt[vbase + 8] = hi;
      } else {
        int OS = (EPI == 0) ? os : N;
        for (int j = 0; j < 2; j++) {
          int rrow = j * 8 + (lane >> 3);
          int ch = (lane & 7) * 8;
          ushortx8 pv = *(const ushortx8*)&Cs16[rrow * 64 + ch];
          *(ushortx8*)&outp[(size_t)(m0 + wm * (TM / 2) + mi * 16 + rrow) * OS +
                            n0 + wn * 64 + ch] = pv;
        }
      }
      __syncthreads();
    }
  }
}

__global__ __launch_bounds__(256) void gemm_qkv(const unsigned short* A,
    const unsigned short* BT, const float* bias, void* out, unsigned short* vt,
    int N, int K) {
  gemm_body<0, 128>(A, BT, bias, nullptr, out, vt, 1536, N, K);
}
__global__ __launch_bounds__(256) void gemm_attnout(const unsigned short* A,
    const unsigned short* BT, const float* bias, const float* resid, void* out,
    int N, int K) {
  gemm_body<2, 64>(A, BT, bias, resid, out, nullptr, N, N, K);
}
__global__ __launch_bounds__(256) void gemm_ffn1(const unsigned short* A,
    const unsigned short* BT, const float* bias, void* out, int N, int K) {
  gemm_body<1, 64>(A, BT, bias, nullptr, out, nullptr, N, N, K);
}
__global__ __launch_bounds__(256) void gemm_ffn2(const unsigned short* A,
    const unsigned short* BT, const float* bias, const float* resid, void* out,
    int N, int K) {
  gemm_body<2, 64>(A, BT, bias, resid, out, nullptr, N, N, K);
}

// ---------------------------------------------------------------------------
// Flash attention v9: K rows stored PERMUTED in LDS so both kf exp-halves
// pack into ONE bf16x8 B-operand -> PV and l-sum use full-rate x32 MFMAs.
// ---------------------------------------------------------------------------
__global__ __launch_bounds__(512, 4) void flash_attn(
    const unsigned short* __restrict__ qk, const unsigned short* __restrict__ v_t,
    unsigned short* __restrict__ o) {
  int flat = blockIdx.y * 16 + blockIdx.x;
  int nf = (flat & 7) * 96 + (flat >> 3);  // 768 blocks, bijective
  int qt = nf % 16;  // 0..15
  int bh = nf / 16;  // 0..47
  int b = bh / 12, h = bh % 12;
  int t = threadIdx.x;
  int w = t >> 6, lane = t & 63, ln = lane & 15, quad = lane >> 4;
  int qg = w & 3, kh2 = w >> 2;  // 32-q group, 32-key half

  __shared__ __align__(16) unsigned short smem[18432];  // 36,864 B
  int qrow0 = b * 2048 + qt * 128;
  int qw = qrow0 + qg * 32;

  // Q as B-operand frags (k=d, n=q), loaded once
  bf16x8 qf[2][2];
  for (int qi = 0; qi < 2; qi++)
    for (int kh = 0; kh < 2; kh++)
      qf[qi][kh] = *(const bf16x8*)&qk[(size_t)(qw + qi * 16 + ln) * 1536 +
                                      h * 64 + kh * 32 + quad * 8];

  UB8 ones8;
#pragma unroll
  for (int r = 0; r < 8; r++) ones8.h8[r] = (bf16_t)1.0f;

  f32x4 zero = {0.f, 0.f, 0.f, 0.f};
  f32x4 o_acc[4][2];  // [df][qi]: O^T partial (this key-half), row=d, col=q
  for (int df = 0; df < 4; df++)
    for (int qi = 0; qi < 2; qi++) o_acc[df][qi] = zero;
  f32x4 l_acc[2] = {zero, zero};  // all 4 regs equal the column sum

  int sr = t >> 3, sc = (t & 7) * 8;  // 512 threads: 64x64 tile in one pass
  // K-row permutation: key bits [b5][b4 b3][b2][b1 b0] -> slot [b5][b2][b4 b3][b1 b0]
  int ssr = (sr & 32) | (((sr >> 2) & 1) << 4) | (((sr >> 3) & 3) << 2) | (sr & 3);
  // prefetch kt=0
  ushortx8 kreg = *(const ushortx8*)&qk[(size_t)(b * 2048 + sr) * 1536 + 768 + h * 64 + sc];
  ushortx8 vreg = *(const ushortx8*)&v_t[(size_t)(bh * 64 + sr) * 2048 + sc];

  for (int kt = 0; kt < 32; kt++) {
    unsigned short* Ks = smem + (kt & 1) * 9216;
    unsigned short* Vt = Ks + 4608;
    // safe: all waves passed barrier kt-1 which drained their kt-2 reads of
    // this parity's buffer
    *(ushortx8*)&Ks[ssr * 72 + sc] = kreg;  // permuted K row placement
    *(ushortx8*)&Vt[sr * 72 + sc] = vreg;
    __syncthreads();
    if (kt < 31) {  // prefetch next tile; overlaps compute below
      int krow0 = b * 2048 + (kt + 1) * 64;
      kreg = *(const ushortx8*)&qk[(size_t)(krow0 + sr) * 1536 + 768 + h * 64 + sc];
      vreg = *(const ushortx8*)&v_t[(size_t)(bh * 64 + sr) * 2048 + (kt + 1) * 64 + sc];
    }

    UB8 pb[2];
#pragma unroll
    for (int kf = 0; kf < 2; kf++) {  // two 16-slot sub-tiles of our key half
      int krow = kh2 * 32 + kf * 16;  // LDS slot base (permuted key order)
      f32x4 ST[2] = {zero, zero};
      bf16x8 kA0 = *(const bf16x8*)&Ks[(krow + ln) * 72 + quad * 8];
      bf16x8 kA1 = *(const bf16x8*)&Ks[(krow + ln) * 72 + 32 + quad * 8];
      __builtin_amdgcn_s_setprio(1);
#pragma unroll
      for (int qi = 0; qi < 2; qi++) {
        ST[qi] = __builtin_amdgcn_mfma_f32_16x16x32_bf16(kA0, qf[qi][0], ST[qi], 0, 0, 0);
        ST[qi] = __builtin_amdgcn_mfma_f32_16x16x32_bf16(kA1, qf[qi][1], ST[qi], 0, 0, 0);
      }
      __builtin_amdgcn_s_setprio(0);
      // lane(quad,r) of kf holds key quad*8 + kf*4 + r (by the sigma perm)
#pragma unroll
      for (int qi = 0; qi < 2; qi++)
#pragma unroll
        for (int r = 0; r < 4; r++)
          pb[qi].h8[kf * 4 + r] = (bf16_t)__builtin_amdgcn_exp2f(ST[qi][r]);
    }
    // pb[qi] is the full 16x16x32 B-operand: col=q(ln), k=key quad*8+j
    __builtin_amdgcn_s_setprio(1);
#pragma unroll
    for (int qi = 0; qi < 2; qi++)
      l_acc[qi] = __builtin_amdgcn_mfma_f32_16x16x32_bf16(ones8.b, pb[qi].b,
                                                          l_acc[qi], 0, 0, 0);
#pragma unroll
    for (int df = 0; df < 4; df++) {
      bf16x8 vA = *(const bf16x8*)&Vt[(df * 16 + ln) * 72 + kh2 * 32 + quad * 8];
#pragma unroll
      for (int qi = 0; qi < 2; qi++)
        o_acc[df][qi] = __builtin_amdgcn_mfma_f32_16x16x32_bf16(vA, pb[qi].b,
                                                                o_acc[df][qi], 0, 0, 0);
    }
    __builtin_amdgcn_s_setprio(0);
  }

  // ---- split-K merge + output ----
  // fb stride 65: bank = (65*q + d) % 32 = (q + d) % 32 -> q-lanes spread
  __syncthreads();  // all compute done; smem reusable
  float* fb = (float*)smem;           // [4 pairs][32q x 65] fp32
  float* fbl = fb + 8320;             // [4 pairs][32q] l partials
  if (kh2 == 1) {
    for (int df = 0; df < 4; df++)
      for (int qi = 0; qi < 2; qi++)
        for (int r = 0; r < 4; r++)
          fb[qg * 2080 + (qi * 16 + ln) * 65 + df * 16 + quad * 4 + r] =
              o_acc[df][qi][r];
    if (quad == 0)
      for (int qi = 0; qi < 2; qi++)
        fbl[qg * 32 + qi * 16 + ln] = l_acc[qi][0];
  }
  __syncthreads();
  float inv[2];
  if (kh2 == 0) {
    for (int qi = 0; qi < 2; qi++) {
      float lt = l_acc[qi][0] + fbl[qg * 32 + qi * 16 + ln];
      inv[qi] = __builtin_amdgcn_rcpf(lt);
    }
    for (int df = 0; df < 4; df++)
      for (int qi = 0; qi < 2; qi++)
        for (int r = 0; r < 4; r++)
          o_acc[df][qi][r] += fb[qg * 2080 + (qi * 16 + ln) * 65 + df * 16 + quad * 4 + r];
  }
  __syncthreads();  // fb reads done before Osm overwrite
  if (kh2 == 0) {
    unsigned short* Osm = smem + qg * 2304;  // 32 x 72
    for (int qi = 0; qi < 2; qi++)
      for (int df = 0; df < 4; df++)
        for (int r = 0; r < 4; r++)
          Osm[(qi * 16 + ln) * 72 + df * 16 + quad * 4 + r] =
              f2bf(o_acc[df][qi][r] * inv[qi]);
  }
  __syncthreads();  // fence scalar ds_writes vs vector ds_reads
  if (kh2 == 0) {
    unsigned short* Osm = smem + qg * 2304;
    for (int p2 = 0; p2 < 4; p2++) {
      int rr = p2 * 8 + (lane >> 3);
      int ch = (lane & 7) * 8;
      ushortx8 u = *(const ushortx8*)&Osm[rr * 72 + ch];
      *(ushortx8*)&o[(size_t)(qw + rr) * 768 + h * 64 + ch] = u;
    }
  }
}

// ---------------------------------------------------------------------------
extern "C" void kernel_launch(void* const* d_in, const int* in_sizes, int n_in,
                              void* d_out, int out_size, void* d_ws, size_t ws_size,
                              hipStream_t stream) {
  const float* hidden = (const float*)d_in[0];
  const float* ln1_g  = (const float*)d_in[1];
  const float* ln1_b  = (const float*)d_in[2];
  const float* w_qkv  = (const float*)d_in[3];
  const float* b_qkv  = (const float*)d_in[4];
  const float* w_attn = (const float*)d_in[5];
  const float* b_attn = (const float*)d_in[6];
  const float* ln2_g  = (const float*)d_in[7];
  const float* ln2_b  = (const float*)d_in[8];
  const float* w_in   = (const float*)d_in[9];
  const float* b_in   = (const float*)d_in[10];
  const float* w_out  = (const float*)d_in[11];
  const float* b_out  = (const float*)d_in[12];
  float* out = (float*)d_out;

  char* ws = (char*)d_ws;
  unsigned short* wqkvT  = (unsigned short*)(ws + 0);         // 2304x768 bf16
  unsigned short* wattnT = (unsigned short*)(ws + 3538944);   //  768x768
  unsigned short* winT   = (unsigned short*)(ws + 4718592);   // 3072x768
  unsigned short* woutT  = (unsigned short*)(ws + 9437184);   //  768x3072
  unsigned short* bufX   = (unsigned short*)(ws + 14155776);  // 8192x768 bf16
  unsigned short* bufBig = (unsigned short*)(ws + 26738688);  // 8192x3072 bf16
  unsigned short* bufQK  = bufBig;                            // 8192x1536 bf16
  unsigned short* v_t    = (unsigned short*)(ws + 26738688 + 25165824);  // V^T

  transpose_all<<<6912, dim3(32, 8), 0, stream>>>(w_qkv, w_attn, w_in, w_out,
                                                  wqkvT, wattnT, winT, woutT);
  ln_kernel<<<8192, 256, 0, stream>>>(hidden, ln1_g, ln1_b, bufX);
  gemm_qkv<<<dim3(18, 64), 256, 0, stream>>>(bufX, wqkvT, b_qkv, (void*)bufQK,
                                             v_t, 2304, 768);
  flash_attn<<<dim3(16, 48), 512, 0, stream>>>(bufQK, v_t, bufX);
  gemm_attnout<<<dim3(6, 128), 256, 0, stream>>>(bufX, wattnT, b_attn, hidden,
                                                 (void*)out, 768, 768);
  ln_kernel<<<8192, 256, 0, stream>>>(out, ln2_g, ln2_b, bufX);
  gemm_ffn1<<<dim3(24, 128), 256, 0, stream>>>(bufX, winT, b_in, (void*)bufBig,
                                               3072, 768);
  gemm_ffn2<<<dim3(6, 128), 256, 0, stream>>>(bufBig, woutT, b_out, out,
                                              (void*)out, 768, 3072);
}

// Round 16
// 367.159 us; speedup vs baseline: 1.1025x; 1.0175x over previous
//
#include <hip/hip_runtime.h>

typedef __bf16 bf16_t;
typedef bf16_t bf16x8 __attribute__((ext_vector_type(8)));
typedef float f32x4 __attribute__((ext_vector_type(4)));
typedef unsigned short ushortx8 __attribute__((ext_vector_type(8)));
typedef unsigned short ushortx4 __attribute__((ext_vector_type(4)));
typedef short short4v __attribute__((ext_vector_type(4)));

union UB8 { bf16_t h8[8]; bf16x8 b; };

// native RNE float->bf16 (gfx950 v_cvt_*_bf16_f32)
__device__ __forceinline__ unsigned short f2bf(float f) {
  union { bf16_t h; unsigned short u; } cv;
  cv.h = (bf16_t)f;
  return cv.u;
}

// async global->LDS, 16B per lane; LDS dest is wave-uniform base + lane*16
__device__ __forceinline__ void gl_lds16(const unsigned short* g, unsigned short* l) {
  __builtin_amdgcn_global_load_lds((const __attribute__((address_space(1))) void*)g,
                                   (__attribute__((address_space(3))) void*)l,
                                   16, 0, 0);
}

// fast GELU: tanh form as sigmoid; max abs err ~3e-4 vs exact erf
__device__ __forceinline__ float gelu_fast(float v) {
  float v3 = v * v * v;
  float z = -2.30211886f * v - 0.102945f * v3;
  float e = exp2f(z);
  return v * __builtin_amdgcn_rcpf(1.0f + e);
}

// ---------------------------------------------------------------------------
// LayerNorm: fp32 [rows x 768] -> bf16 bits [rows x 768]
// ---------------------------------------------------------------------------
__global__ __launch_bounds__(256) void ln_kernel(const float* __restrict__ x,
                                                 const float* __restrict__ g,
                                                 const float* __restrict__ b,
                                                 unsigned short* __restrict__ out) {
  int row = blockIdx.x;
  int t = threadIdx.x;
  const float* xr = x + (size_t)row * 768;
  float v0 = xr[t], v1 = xr[t + 256], v2 = xr[t + 512];
  __shared__ float red[4];
  float s = v0 + v1 + v2;
  for (int o = 32; o > 0; o >>= 1) s += __shfl_down(s, o, 64);
  if ((t & 63) == 0) red[t >> 6] = s;
  __syncthreads();
  float mu = (red[0] + red[1] + red[2] + red[3]) * (1.0f / 768.0f);
  __syncthreads();
  float d0 = v0 - mu, d1 = v1 - mu, d2 = v2 - mu;
  s = d0 * d0 + d1 * d1 + d2 * d2;
  for (int o = 32; o > 0; o >>= 1) s += __shfl_down(s, o, 64);
  if ((t & 63) == 0) red[t >> 6] = s;
  __syncthreads();
  float var = (red[0] + red[1] + red[2] + red[3]) * (1.0f / 768.0f);
  float rs = rsqrtf(var + 1e-6f);
  unsigned short* orow = out + (size_t)row * 768;
  orow[t]       = f2bf(d0 * rs * g[t]       + b[t]);
  orow[t + 256] = f2bf(d1 * rs * g[t + 256] + b[t + 256]);
  orow[t + 512] = f2bf(d2 * rs * g[t + 512] + b[t + 512]);
}

// ---------------------------------------------------------------------------
// All 4 weight transposes in ONE launch. fp32 [K x N] -> bf16 [N x K].
// ---------------------------------------------------------------------------
__global__ __launch_bounds__(256) void transpose_all(
    const float* __restrict__ w_qkv, const float* __restrict__ w_attn,
    const float* __restrict__ w_in, const float* __restrict__ w_out,
    unsigned short* __restrict__ wqkvT, unsigned short* __restrict__ wattnT,
    unsigned short* __restrict__ winT, unsigned short* __restrict__ woutT) {
  int id = blockIdx.x;
  const float* W; unsigned short* WT; int K, N, nx, ny;
  if (id < 1728)      { W = w_qkv;  WT = wqkvT;  K = 768;  N = 2304; nx = id % 72; ny = id / 72; }
  else if (id < 2304) { id -= 1728; W = w_attn; WT = wattnT; K = 768;  N = 768;  nx = id % 24; ny = id / 24; }
  else if (id < 4608) { id -= 2304; W = w_in;   WT = winT;   K = 768;  N = 3072; nx = id % 96; ny = id / 96; }
  else                { id -= 4608; W = w_out;  WT = woutT;  K = 3072; N = 768;  nx = id % 24; ny = id / 24; }
  __shared__ float tile[32][33];
  int n0 = nx * 32, k0 = ny * 32;
  int tx = threadIdx.x, ty = threadIdx.y;
  for (int i = 0; i < 4; i++)
    tile[ty + i * 8][tx] = W[(size_t)(k0 + ty + i * 8) * N + n0 + tx];
  __syncthreads();
  for (int i = 0; i < 4; i++)
    WT[(size_t)(n0 + ty + i * 8) * K + k0 + tx] = f2bf(tile[tx][ty + i * 8]);
}

// ---------------------------------------------------------------------------
// GEMM body v22 = v21 + BANDED L2 traversal inside each XCD chunk. The T1
// remap gives each XCD a contiguous nf range, but decoding n-fastest made
// every m-group re-sweep ALL of B (ffn1: 4.7MB > 4MB L2 -> thrash once per
// m-group; FETCH 147MB = 9x inputs). Banded decode (BH=8): within a band of
// 8 m-groups, m varies fastest -> the 196KB B-panel stays L2-hot across the
// band and B is fetched once per band (16x fewer refetches at ffn1). Pure
// index remap: bijective (my%8==0 for all kernels; chunk = whole bands),
// no sync/staging/numeric change.
// ---------------------------------------------------------------------------
template <int EPI, int TM>
__device__ __forceinline__ void gemm_body(const unsigned short* __restrict__ A,
                                          const unsigned short* __restrict__ BT,
                                          const float* __restrict__ bias,
                                          const float* resid,
                                          void* out, unsigned short* vt, int os,
                                          int N, int K) {
  constexpr int BK = 32, MI = TM / 32;
  constexpr int ASZ = TM * BK;        // shorts per A sub-buffer
  constexpr int BUF = ASZ + 128 * BK; // shorts per pipeline buffer
  __shared__ __align__(16) unsigned short smem[4 * BUF];

  int t = threadIdx.x;
  int w = t >> 6, lane = t & 63, ln = lane & 15, quad = lane >> 4;
  int wm = w & 1, wn = w >> 1;

  // T1: bijective XCD chunk remap (all grids are multiples of 8)
  int gx = gridDim.x;
  int nwg = gx * gridDim.y;
  int flat = blockIdx.y * gx + blockIdx.x;
  int nf = (flat & 7) * (nwg >> 3) + (flat >> 3);
  // banded decode: bands of 8 m-groups, m fastest within the band
  int band = nf / (8 * gx);
  int r = nf - band * (8 * gx);
  int m0 = (band * 8 + (r & 7)) * TM;
  int n0 = (r >> 3) * 128;

  int lrow = lane >> 2;   // 0..15: row within 16-row load chunk
  int lslot = lane & 3;   // 16B slot within row
  int scol = (lslot ^ ((lrow >> 1) & 3)) * 8;  // pre-swizzled global column

  const unsigned short* gA0 = A + (size_t)(m0 + w * 16 + lrow) * K + scol;
  const unsigned short* gA1 = gA0 + (size_t)64 * K;
  const unsigned short* gB0 = BT + (size_t)(n0 + w * 16 + lrow) * K + scol;
  const unsigned short* gB1 = gB0 + (size_t)64 * K;

  auto stage = [&](int buf) {
    unsigned short* Sb = smem + buf * BUF;
    gl_lds16(gA0, Sb + w * 512);
    gA0 += BK;
    if constexpr (TM == 128) { gl_lds16(gA1, Sb + 2048 + w * 512); gA1 += BK; }
    gl_lds16(gB0, Sb + ASZ + w * 512);
    gl_lds16(gB1, Sb + ASZ + 2048 + w * 512);
    gB0 += BK; gB1 += BK;
  };

  f32x4 acc[MI][4];
  f32x4 zero = {0.f, 0.f, 0.f, 0.f};
  for (int mi = 0; mi < MI; mi++)
    for (int ni = 0; ni < 4; ni++) acc[mi][ni] = zero;

  int soff = (quad ^ ((ln >> 1) & 3)) * 8;  // fragment slot (inverse swizzle)

  auto compute = [&](int kt) {
    const unsigned short* Sc = smem + (kt & 3) * BUF;
    bf16x8 af[MI], bfr[4];
#pragma unroll
    for (int mi = 0; mi < MI; mi++)
      af[mi] = *(const bf16x8*)&Sc[(wm * (TM / 2) + mi * 16 + ln) * 32 + soff];
#pragma unroll
    for (int ni = 0; ni < 4; ni++)
      bfr[ni] = *(const bf16x8*)&Sc[ASZ + (wn * 64 + ni * 16 + ln) * 32 + soff];
    __builtin_amdgcn_s_setprio(1);
#pragma unroll
    for (int mi = 0; mi < MI; mi++)
#pragma unroll
      for (int ni = 0; ni < 4; ni++)
        acc[mi][ni] = __builtin_amdgcn_mfma_f32_16x16x32_bf16(af[mi], bfr[ni],
                                                              acc[mi][ni], 0, 0, 0);
    __builtin_amdgcn_s_setprio(0);
  };

  int nk = K / BK;  // 24 or 96: always >= 4 and even
  stage(0); stage(1);  // ONE iteration's worth only
  for (int kt = 0; kt < nk; kt += 2) {
    // only the {kt,kt+1} stage batches are outstanding: free drain
    asm volatile("s_waitcnt vmcnt(0)" ::: "memory");
    __builtin_amdgcn_s_barrier();
    __builtin_amdgcn_sched_barrier(0);
    if (kt + 2 < nk) {  // fill bufs of {kt-2,kt-1}: consumed pre-barrier
      stage((kt + 2) & 3);
      stage((kt + 3) & 3);
    }
    compute(kt);
    compute(kt + 1);
  }

  if (EPI == 2) {
    float* outp = (float*)out;
    for (int mi = 0; mi < MI; mi++) {
      for (int ni = 0; ni < 4; ni++) {
        int col = n0 + wn * 64 + ni * 16 + ln;
        float bv = bias[col];
        for (int r2 = 0; r2 < 4; r2++) {
          int row = m0 + wm * (TM / 2) + mi * 16 + quad * 4 + r2;
          float v = acc[mi][ni][r2] + bv;
          v += resid[(size_t)row * N + col];
          outp[(size_t)row * N + col] = v;
        }
      }
    }
  } else {
    __syncthreads();  // all waves done with K-loop smem before Cs16 reuse
    unsigned short* Cs16 = smem + w * 1024;
    unsigned short* outp = (unsigned short*)out;
    for (int mi = 0; mi < MI; mi++) {
      for (int ni = 0; ni < 4; ni++) {
        int col = n0 + wn * 64 + ni * 16 + ln;
        float bv = bias[col];
        for (int r2 = 0; r2 < 4; r2++) {
          float v = acc[mi][ni][r2] + bv;
          if (EPI == 0) {
            if (col < 768) v *= 0.18033688f;  // hd^-0.5 * log2(e)
          } else {
            v = gelu_fast(v);
          }
          Cs16[(quad * 4 + r2) * 64 + ni * 16 + ln] = f2bf(v);
        }
      }
      __syncthreads();  // fence: scalar ds_writes visible before reads
      if (EPI == 0 && n0 >= 1536) {
        int c = n0 - 1536 + wn * 64 + lane;  // h*64+d
        int s0 = m0 + wm * (TM / 2) + mi * 16;
        int bb = s0 >> 11, sl = s0 & 2047;
        ushortx8 lo, hi;
        for (int r2 = 0; r2 < 8; r2++) lo[r2] = Cs16[r2 * 64 + lane];
        for (int r2 = 0; r2 < 8; r2++) hi[r2] = Cs16[(8 + r2) * 64 + lane];
        size_t vbase = ((size_t)(bb * 768 + c)) * 2048 + sl;
        *(ushortx8*)&vt[vbase] = lo;
        *(ushortx8*)&vt[vbase + 8] = hi;
      } else {
        int OS = (EPI == 0) ? os : N;
        for (int j = 0; j < 2; j++) {
          int rrow = j * 8 + (lane >> 3);
          int ch = (lane & 7) * 8;
          ushortx8 pv = *(const ushortx8*)&Cs16[rrow * 64 + ch];
          *(ushortx8*)&outp[(size_t)(m0 + wm * (TM / 2) + mi * 16 + rrow) * OS +
                            n0 + wn * 64 + ch] = pv;
        }
      }
      __syncthreads();
    }
  }
}

__global__ __launch_bounds__(256) void gemm_qkv(const unsigned short* A,
    const unsigned short* BT, const float* bias, void* out, unsigned short* vt,
    int N, int K) {
  gemm_body<0, 128>(A, BT, bias, nullptr, out, vt, 1536, N, K);
}
__global__ __launch_bounds__(256) void gemm_attnout(const unsigned short* A,
    const unsigned short* BT, const float* bias, const float* resid, void* out,
    int N, int K) {
  gemm_body<2, 64>(A, BT, bias, resid, out, nullptr, N, N, K);
}
__global__ __launch_bounds__(256) void gemm_ffn1(const unsigned short* A,
    const unsigned short* BT, const float* bias, void* out, int N, int K) {
  gemm_body<1, 64>(A, BT, bias, nullptr, out, nullptr, N, N, K);
}
__global__ __launch_bounds__(256) void gemm_ffn2(const unsigned short* A,
    const unsigned short* BT, const float* bias, const float* resid, void* out,
    int N, int K) {
  gemm_body<2, 64>(A, BT, bias, resid, out, nullptr, N, N, K);
}

// ---------------------------------------------------------------------------
// Flash attention v9: K rows stored PERMUTED in LDS so both kf exp-halves
// pack into ONE bf16x8 B-operand -> PV and l-sum use full-rate x32 MFMAs.
// ---------------------------------------------------------------------------
__global__ __launch_bounds__(512, 4) void flash_attn(
    const unsigned short* __restrict__ qk, const unsigned short* __restrict__ v_t,
    unsigned short* __restrict__ o) {
  int flat = blockIdx.y * 16 + blockIdx.x;
  int nf = (flat & 7) * 96 + (flat >> 3);  // 768 blocks, bijective
  int qt = nf % 16;  // 0..15
  int bh = nf / 16;  // 0..47
  int b = bh / 12, h = bh % 12;
  int t = threadIdx.x;
  int w = t >> 6, lane = t & 63, ln = lane & 15, quad = lane >> 4;
  int qg = w & 3, kh2 = w >> 2;  // 32-q group, 32-key half

  __shared__ __align__(16) unsigned short smem[18432];  // 36,864 B
  int qrow0 = b * 2048 + qt * 128;
  int qw = qrow0 + qg * 32;

  // Q as B-operand frags (k=d, n=q), loaded once
  bf16x8 qf[2][2];
  for (int qi = 0; qi < 2; qi++)
    for (int kh = 0; kh < 2; kh++)
      qf[qi][kh] = *(const bf16x8*)&qk[(size_t)(qw + qi * 16 + ln) * 1536 +
                                      h * 64 + kh * 32 + quad * 8];

  UB8 ones8;
#pragma unroll
  for (int r = 0; r < 8; r++) ones8.h8[r] = (bf16_t)1.0f;

  f32x4 zero = {0.f, 0.f, 0.f, 0.f};
  f32x4 o_acc[4][2];  // [df][qi]: O^T partial (this key-half), row=d, col=q
  for (int df = 0; df < 4; df++)
    for (int qi = 0; qi < 2; qi++) o_acc[df][qi] = zero;
  f32x4 l_acc[2] = {zero, zero};  // all 4 regs equal the column sum

  int sr = t >> 3, sc = (t & 7) * 8;  // 512 threads: 64x64 tile in one pass
  // K-row permutation: key bits [b5][b4 b3][b2][b1 b0] -> slot [b5][b2][b4 b3][b1 b0]
  int ssr = (sr & 32) | (((sr >> 2) & 1) << 4) | (((sr >> 3) & 3) << 2) | (sr & 3);
  // prefetch kt=0
  ushortx8 kreg = *(const ushortx8*)&qk[(size_t)(b * 2048 + sr) * 1536 + 768 + h * 64 + sc];
  ushortx8 vreg = *(const ushortx8*)&v_t[(size_t)(bh * 64 + sr) * 2048 + sc];

  for (int kt = 0; kt < 32; kt++) {
    unsigned short* Ks = smem + (kt & 1) * 9216;
    unsigned short* Vt = Ks + 4608;
    // safe: all waves passed barrier kt-1 which drained their kt-2 reads of
    // this parity's buffer
    *(ushortx8*)&Ks[ssr * 72 + sc] = kreg;  // permuted K row placement
    *(ushortx8*)&Vt[sr * 72 + sc] = vreg;
    __syncthreads();
    if (kt < 31) {  // prefetch next tile; overlaps compute below
      int krow0 = b * 2048 + (kt + 1) * 64;
      kreg = *(const ushortx8*)&qk[(size_t)(krow0 + sr) * 1536 + 768 + h * 64 + sc];
      vreg = *(const ushortx8*)&v_t[(size_t)(bh * 64 + sr) * 2048 + (kt + 1) * 64 + sc];
    }

    UB8 pb[2];
#pragma unroll
    for (int kf = 0; kf < 2; kf++) {  // two 16-slot sub-tiles of our key half
      int krow = kh2 * 32 + kf * 16;  // LDS slot base (permuted key order)
      f32x4 ST[2] = {zero, zero};
      bf16x8 kA0 = *(const bf16x8*)&Ks[(krow + ln) * 72 + quad * 8];
      bf16x8 kA1 = *(const bf16x8*)&Ks[(krow + ln) * 72 + 32 + quad * 8];
      __builtin_amdgcn_s_setprio(1);
#pragma unroll
      for (int qi = 0; qi < 2; qi++) {
        ST[qi] = __builtin_amdgcn_mfma_f32_16x16x32_bf16(kA0, qf[qi][0], ST[qi], 0, 0, 0);
        ST[qi] = __builtin_amdgcn_mfma_f32_16x16x32_bf16(kA1, qf[qi][1], ST[qi], 0, 0, 0);
      }
      __builtin_amdgcn_s_setprio(0);
      // lane(quad,r) of kf holds key quad*8 + kf*4 + r (by the sigma perm)
#pragma unroll
      for (int qi = 0; qi < 2; qi++)
#pragma unroll
        for (int r = 0; r < 4; r++)
          pb[qi].h8[kf * 4 + r] = (bf16_t)__builtin_amdgcn_exp2f(ST[qi][r]);
    }
    // pb[qi] is the full 16x16x32 B-operand: col=q(ln), k=key quad*8+j
    __builtin_amdgcn_s_setprio(1);
#pragma unroll
    for (int qi = 0; qi < 2; qi++)
      l_acc[qi] = __builtin_amdgcn_mfma_f32_16x16x32_bf16(ones8.b, pb[qi].b,
                                                          l_acc[qi], 0, 0, 0);
#pragma unroll
    for (int df = 0; df < 4; df++) {
      bf16x8 vA = *(const bf16x8*)&Vt[(df * 16 + ln) * 72 + kh2 * 32 + quad * 8];
#pragma unroll
      for (int qi = 0; qi < 2; qi++)
        o_acc[df][qi] = __builtin_amdgcn_mfma_f32_16x16x32_bf16(vA, pb[qi].b,
                                                                o_acc[df][qi], 0, 0, 0);
    }
    __builtin_amdgcn_s_setprio(0);
  }

  // ---- split-K merge + output ----
  // fb stride 65: bank = (65*q + d) % 32 = (q + d) % 32 -> q-lanes spread
  __syncthreads();  // all compute done; smem reusable
  float* fb = (float*)smem;           // [4 pairs][32q x 65] fp32
  float* fbl = fb + 8320;             // [4 pairs][32q] l partials
  if (kh2 == 1) {
    for (int df = 0; df < 4; df++)
      for (int qi = 0; qi < 2; qi++)
        for (int r = 0; r < 4; r++)
          fb[qg * 2080 + (qi * 16 + ln) * 65 + df * 16 + quad * 4 + r] =
              o_acc[df][qi][r];
    if (quad == 0)
      for (int qi = 0; qi < 2; qi++)
        fbl[qg * 32 + qi * 16 + ln] = l_acc[qi][0];
  }
  __syncthreads();
  float inv[2];
  if (kh2 == 0) {
    for (int qi = 0; qi < 2; qi++) {
      float lt = l_acc[qi][0] + fbl[qg * 32 + qi * 16 + ln];
      inv[qi] = __builtin_amdgcn_rcpf(lt);
    }
    for (int df = 0; df < 4; df++)
      for (int qi = 0; qi < 2; qi++)
        for (int r = 0; r < 4; r++)
          o_acc[df][qi][r] += fb[qg * 2080 + (qi * 16 + ln) * 65 + df * 16 + quad * 4 + r];
  }
  __syncthreads();  // fb reads done before Osm overwrite
  if (kh2 == 0) {
    unsigned short* Osm = smem + qg * 2304;  // 32 x 72
    for (int qi = 0; qi < 2; qi++)
      for (int df = 0; df < 4; df++)
        for (int r = 0; r < 4; r++)
          Osm[(qi * 16 + ln) * 72 + df * 16 + quad * 4 + r] =
              f2bf(o_acc[df][qi][r] * inv[qi]);
  }
  __syncthreads();  // fence scalar ds_writes vs vector ds_reads
  if (kh2 == 0) {
    unsigned short* Osm = smem + qg * 2304;
    for (int p2 = 0; p2 < 4; p2++) {
      int rr = p2 * 8 + (lane >> 3);
      int ch = (lane & 7) * 8;
      ushortx8 u = *(const ushortx8*)&Osm[rr * 72 + ch];
      *(ushortx8*)&o[(size_t)(qw + rr) * 768 + h * 64 + ch] = u;
    }
  }
}

// ---------------------------------------------------------------------------
extern "C" void kernel_launch(void* const* d_in, const int* in_sizes, int n_in,
                              void* d_out, int out_size, void* d_ws, size_t ws_size,
                              hipStream_t stream) {
  const float* hidden = (const float*)d_in[0];
  const float* ln1_g  = (const float*)d_in[1];
  const float* ln1_b  = (const float*)d_in[2];
  const float* w_qkv  = (const float*)d_in[3];
  const float* b_qkv  = (const float*)d_in[4];
  const float* w_attn = (const float*)d_in[5];
  const float* b_attn = (const float*)d_in[6];
  const float* ln2_g  = (const float*)d_in[7];
  const float* ln2_b  = (const float*)d_in[8];
  const float* w_in   = (const float*)d_in[9];
  const float* b_in   = (const float*)d_in[10];
  const float* w_out  = (const float*)d_in[11];
  const float* b_out  = (const float*)d_in[12];
  float* out = (float*)d_out;

  char* ws = (char*)d_ws;
  unsigned short* wqkvT  = (unsigned short*)(ws + 0);         // 2304x768 bf16
  unsigned short* wattnT = (unsigned short*)(ws + 3538944);   //  768x768
  unsigned short* winT   = (unsigned short*)(ws + 4718592);   // 3072x768
  unsigned short* woutT  = (unsigned short*)(ws + 9437184);   //  768x3072
  unsigned short* bufX   = (unsigned short*)(ws + 14155776);  // 8192x768 bf16
  unsigned short* bufBig = (unsigned short*)(ws + 26738688);  // 8192x3072 bf16
  unsigned short* bufQK  = bufBig;                            // 8192x1536 bf16
  unsigned short* v_t    = (unsigned short*)(ws + 26738688 + 25165824);  // V^T

  transpose_all<<<6912, dim3(32, 8), 0, stream>>>(w_qkv, w_attn, w_in, w_out,
                                                  wqkvT, wattnT, winT, woutT);
  ln_kernel<<<8192, 256, 0, stream>>>(hidden, ln1_g, ln1_b, bufX);
  gemm_qkv<<<dim3(18, 64), 256, 0, stream>>>(bufX, wqkvT, b_qkv, (void*)bufQK,
                                             v_t, 2304, 768);
  flash_attn<<<dim3(16, 48), 512, 0, stream>>>(bufQK, v_t, bufX);
  gemm_attnout<<<dim3(6, 128), 256, 0, stream>>>(bufX, wattnT, b_attn, hidden,
                                                 (void*)out, 768, 768);
  ln_kernel<<<8192, 256, 0, stream>>>(out, ln2_g, ln2_b, bufX);
  gemm_ffn1<<<dim3(24, 128), 256, 0, stream>>>(bufX, winT, b_in, (void*)bufBig,
                                               3072, 768);
  gemm_ffn2<<<dim3(6, 128), 256, 0, stream>>>(bufBig, woutT, b_out, out,
                                              (void*)out, 768, 3072);
}